// Round 1
// baseline (734.339 us; speedup 1.0000x reference)
//
#include <hip/hip_runtime.h>
#include <math.h>

// Problem constants
static constexpr int Bsz = 32, Nseq = 49, Dm = 512, Hh = 8, DKh = 64, NRELc = 14;
static constexpr int Mrows = Bsz * Nseq;       // 1568
static constexpr float SCALEC = 0.125f;        // 1/sqrt(64)
#define EPSV 1e-5f

// ---------- helpers ----------
__device__ inline float wsum(float v) {
#pragma unroll
  for (int m = 32; m >= 1; m >>= 1) v += __shfl_xor(v, m, 64);
  return v;
}
__device__ inline float wmax(float v) {
#pragma unroll
  for (int m = 32; m >= 1; m >>= 1) v = fmaxf(v, __shfl_xor(v, m, 64));
  return v;
}

// ---------- K0a: transpose convW [o][c][t] -> Wt [t][c][o] (t = di*3+dj) ----------
__global__ __launch_bounds__(256) void transposeW(const float* __restrict__ convW,
                                                  float* __restrict__ Wt) {
  int idx = blockIdx.x * 256 + threadIdx.x;  // over o*512+c (262144)
  if (idx >= 262144) return;
  int o = idx >> 9, c = idx & 511;
  const float* src = convW + (size_t)o * 4608 + c * 9;
#pragma unroll
  for (int t = 0; t < 9; t++)
    Wt[(size_t)t * 262144 + c * 512 + o] = src[t];
}

// ---------- K0b: small precomputes: crel[14], wrg[512], cconst ----------
__global__ __launch_bounds__(256) void smalls_kernel(
    const float* __restrict__ Wproj, const float* __restrict__ Wgate,
    const float* __restrict__ rel_embed, const float* __restrict__ bproj,
    const float* __restrict__ br2, const float* __restrict__ bgate,
    const float* __restrict__ Wr2, float* __restrict__ crel,
    float* __restrict__ wrg, float* __restrict__ cconst) {
  int tid = threadIdx.x;
  if (blockIdx.x == 0) {
    __shared__ float pg[64];
    if (tid < 64) {
      float s = 0.f;
      for (int d = 0; d < 512; d++) s += Wproj[tid * 512 + d] * Wgate[d];
      pg[tid] = s;
    }
    __syncthreads();
    if (tid < 14) {
      float s = 0.f;
      for (int dk = 0; dk < 64; dk++) s += rel_embed[tid * 64 + dk] * pg[dk];
      crel[tid] = s;
    }
    if (tid == 64) {
      float s = 0.f;
      for (int d = 0; d < 512; d++) s += (bproj[d] + br2[d]) * Wgate[d];
      cconst[0] = s + bgate[0];
    }
  } else {
    int d = (blockIdx.x - 1) * 256 + tid;  // 0..511
    float s = 0.f;
    for (int d2 = 0; d2 < 512; d2++) s += Wr2[(size_t)d * 512 + d2] * Wgate[d2];
    wrg[d] = s;
  }
}

// ---------- K1: conv3x3 as implicit-im2col GEMM: h[m=(b,p)][o] ----------
__global__ __launch_bounds__(256) void conv_gemm(const float* __restrict__ Q,
                                                 const float* __restrict__ Wt,
                                                 const float* __restrict__ convb,
                                                 float* __restrict__ h) {
  int n0 = blockIdx.x * 64;
  int m0 = blockIdx.y * 64;
  __shared__ float As[16][65];
  __shared__ float Bs[16][64];
  int tid = threadIdx.x;
  int tx = tid & 15, ty = tid >> 4;
  int aRow = tid >> 2, aCol = (tid & 3) << 2;
  int bRow = tid >> 4, bCol = (tid & 15) << 2;
  int m = m0 + aRow;
  int bb = m / 49, p = m % 49, pi = p / 7, pj = p % 7;
  float acc[4][4] = {};
  for (int k0 = 0; k0 < 4608; k0 += 16) {
    int t = k0 >> 9;
    int cq = (k0 & 511) + aCol;
    float4 av = make_float4(0.f, 0.f, 0.f, 0.f);
    if (m < Mrows) {
      int ii = pi + (t / 3) - 1, jj = pj + (t % 3) - 1;
      if ((unsigned)ii < 7u && (unsigned)jj < 7u)
        av = *(const float4*)(Q + (((size_t)(bb * 49 + ii * 7 + jj)) << 9) + cq);
    }
    As[aCol + 0][aRow] = av.x;
    As[aCol + 1][aRow] = av.y;
    As[aCol + 2][aRow] = av.z;
    As[aCol + 3][aRow] = av.w;
    *(float4*)&Bs[bRow][bCol] =
        *(const float4*)(Wt + (size_t)(k0 + bRow) * 512 + n0 + bCol);
    __syncthreads();
#pragma unroll
    for (int kk = 0; kk < 16; kk++) {
      float a0 = As[kk][ty * 4 + 0], a1 = As[kk][ty * 4 + 1];
      float a2 = As[kk][ty * 4 + 2], a3 = As[kk][ty * 4 + 3];
      float4 b4 = *(const float4*)&Bs[kk][tx * 4];
      acc[0][0] = fmaf(a0, b4.x, acc[0][0]); acc[0][1] = fmaf(a0, b4.y, acc[0][1]);
      acc[0][2] = fmaf(a0, b4.z, acc[0][2]); acc[0][3] = fmaf(a0, b4.w, acc[0][3]);
      acc[1][0] = fmaf(a1, b4.x, acc[1][0]); acc[1][1] = fmaf(a1, b4.y, acc[1][1]);
      acc[1][2] = fmaf(a1, b4.z, acc[1][2]); acc[1][3] = fmaf(a1, b4.w, acc[1][3]);
      acc[2][0] = fmaf(a2, b4.x, acc[2][0]); acc[2][1] = fmaf(a2, b4.y, acc[2][1]);
      acc[2][2] = fmaf(a2, b4.z, acc[2][2]); acc[2][3] = fmaf(a2, b4.w, acc[2][3]);
      acc[3][0] = fmaf(a3, b4.x, acc[3][0]); acc[3][1] = fmaf(a3, b4.y, acc[3][1]);
      acc[3][2] = fmaf(a3, b4.z, acc[3][2]); acc[3][3] = fmaf(a3, b4.w, acc[3][3]);
    }
    __syncthreads();
  }
#pragma unroll
  for (int i = 0; i < 4; i++) {
    int mm = m0 + ty * 4 + i;
    if (mm >= Mrows) continue;
#pragma unroll
    for (int j = 0; j < 4; j++) {
      int n = n0 + tx * 4 + j;
      h[(size_t)mm * 512 + n] = acc[i][j] + convb[n];
    }
  }
}

// ---------- K2: BatchNorm stats per output channel over (B, 49) ----------
__global__ __launch_bounds__(256) void bn_stats(const float* __restrict__ h,
                                                float* __restrict__ mu,
                                                float* __restrict__ rsg) {
  int c = blockIdx.x;
  int tid = threadIdx.x;
  float s = 0.f, ss = 0.f;
  for (int r = tid; r < Mrows; r += 256) {
    float v = h[(size_t)r * 512 + c];
    s += v;
    ss += v * v;
  }
  s = wsum(s);
  ss = wsum(ss);
  __shared__ float r1[4], r2[4];
  int wave = tid >> 6, lane = tid & 63;
  if (lane == 0) { r1[wave] = s; r2[wave] = ss; }
  __syncthreads();
  if (tid == 0) {
    float S = r1[0] + r1[1] + r1[2] + r1[3];
    float SS = r2[0] + r2[1] + r2[2] + r2[3];
    float m = S / (float)Mrows;
    float var = SS / (float)Mrows - m * m;
    mu[c] = m;
    rsg[c] = rsqrtf(var + EPSV);
  }
}

// ---------- K3: xs = relu(bn(h)); eq/ek/ev = xs + {q,k,v} ----------
__global__ __launch_bounds__(256) void fuse_xs(
    const float* __restrict__ h, const float* __restrict__ mu,
    const float* __restrict__ rsg, const float* __restrict__ Q,
    const float* __restrict__ Kin, const float* __restrict__ Vin,
    float* __restrict__ eq, float* __restrict__ ek, float* __restrict__ ev) {
  int i = blockIdx.x * 256 + threadIdx.x;
  if (i >= Mrows * 512) return;
  int c = i & 511;
  float xs = fmaxf((h[i] - mu[c]) * rsg[c], 0.f);
  eq[i] = xs + Q[i];
  ek[i] = xs + Kin[i];
  ev[i] = xs + Vin[i];
}

// ---------- generic batched tiled GEMM: C[z] = A[z] @ B[z] (+bias) ----------
struct GemmJobs {
  const float* A[7];
  const float* Bm[7];
  const float* bias[7];
  float* C[7];
  int N[7];
};

__global__ __launch_bounds__(256) void gemm_multi(GemmJobs jobs, int M, int K) {
  int z = blockIdx.z;
  int N = jobs.N[z];
  int n0 = blockIdx.x * 64;
  if (n0 >= N) return;
  int m0 = blockIdx.y * 64;
  const float* A = jobs.A[z];
  const float* Bm = jobs.Bm[z];
  const float* bias = jobs.bias[z];
  float* C = jobs.C[z];
  __shared__ float As[16][65];
  __shared__ float Bs[16][64];
  int tid = threadIdx.x;
  int tx = tid & 15, ty = tid >> 4;
  int aRow = tid >> 2, aCol = (tid & 3) << 2;
  int bRow = tid >> 4, bCol = (tid & 15) << 2;
  float acc[4][4] = {};
  for (int k0 = 0; k0 < K; k0 += 16) {
    float4 av = make_float4(0.f, 0.f, 0.f, 0.f);
    if (m0 + aRow < M)
      av = *(const float4*)(A + (size_t)(m0 + aRow) * K + k0 + aCol);
    As[aCol + 0][aRow] = av.x;
    As[aCol + 1][aRow] = av.y;
    As[aCol + 2][aRow] = av.z;
    As[aCol + 3][aRow] = av.w;
    *(float4*)&Bs[bRow][bCol] =
        *(const float4*)(Bm + (size_t)(k0 + bRow) * N + n0 + bCol);
    __syncthreads();
#pragma unroll
    for (int kk = 0; kk < 16; kk++) {
      float a0 = As[kk][ty * 4 + 0], a1 = As[kk][ty * 4 + 1];
      float a2 = As[kk][ty * 4 + 2], a3 = As[kk][ty * 4 + 3];
      float4 b4 = *(const float4*)&Bs[kk][tx * 4];
      acc[0][0] = fmaf(a0, b4.x, acc[0][0]); acc[0][1] = fmaf(a0, b4.y, acc[0][1]);
      acc[0][2] = fmaf(a0, b4.z, acc[0][2]); acc[0][3] = fmaf(a0, b4.w, acc[0][3]);
      acc[1][0] = fmaf(a1, b4.x, acc[1][0]); acc[1][1] = fmaf(a1, b4.y, acc[1][1]);
      acc[1][2] = fmaf(a1, b4.z, acc[1][2]); acc[1][3] = fmaf(a1, b4.w, acc[1][3]);
      acc[2][0] = fmaf(a2, b4.x, acc[2][0]); acc[2][1] = fmaf(a2, b4.y, acc[2][1]);
      acc[2][2] = fmaf(a2, b4.z, acc[2][2]); acc[2][3] = fmaf(a2, b4.w, acc[2][3]);
      acc[3][0] = fmaf(a3, b4.x, acc[3][0]); acc[3][1] = fmaf(a3, b4.y, acc[3][1]);
      acc[3][2] = fmaf(a3, b4.z, acc[3][2]); acc[3][3] = fmaf(a3, b4.w, acc[3][3]);
    }
    __syncthreads();
  }
#pragma unroll
  for (int i = 0; i < 4; i++) {
    int m = m0 + ty * 4 + i;
    if (m >= M) continue;
#pragma unroll
    for (int j = 0; j < 4; j++) {
      int n = n0 + tx * 4 + j;
      float bv = bias ? bias[n] : 0.f;
      C[(size_t)m * N + n] = acc[i][j] + bv;
    }
  }
}

// ---------- K5: per-pair gate factor (1 + sigmoid(...)) ----------
// One wave per (b,q,k) pair.
__global__ __launch_bounds__(256) void pair_gate(
    const float* __restrict__ Cq, const float* __restrict__ Ck,
    const float* __restrict__ Rq, const float* __restrict__ Rk,
    const float* __restrict__ Wc2, const float* __restrict__ bc2,
    const float* __restrict__ gc, const float* __restrict__ bcln,
    const float* __restrict__ gr, const float* __restrict__ brln,
    const float* __restrict__ crel, const float* __restrict__ wrg,
    const float* __restrict__ cconstp, float* __restrict__ gfac) {
  __shared__ float sW[14 * 256];  // transposed: sW[r*256 + d] = Wc2[d][r]
  __shared__ float sgc[256], sbc[256];
  __shared__ float sgr[512], sbr[512], swg[512];
  __shared__ float scl[14], sb2[14];
  int tid = threadIdx.x;
  for (int i = tid; i < 14 * 256; i += 256) {
    int r = i >> 8, d = i & 255;
    sW[i] = Wc2[d * 14 + r];
  }
  sgc[tid] = gc[tid];
  sbc[tid] = bcln[tid];
  sgr[tid] = gr[tid]; sgr[tid + 256] = gr[tid + 256];
  sbr[tid] = brln[tid]; sbr[tid + 256] = brln[tid + 256];
  swg[tid] = wrg[tid]; swg[tid + 256] = wrg[tid + 256];
  if (tid < 14) { scl[tid] = crel[tid]; sb2[tid] = bc2[tid]; }
  __syncthreads();
  float cconst = cconstp[0];
  int wave = tid >> 6, lane = tid & 63;
  int pid = blockIdx.x * 4 + wave;   // 76832 pairs = 19208*4 exactly
  int b = pid / 2401;
  int r2 = pid % 2401;
  int q = r2 / 49, kk = r2 % 49;
  int d4 = lane * 4;

  // ---- classifier branch: 256-d LN -> relu -> @Wc2 -> softmax dot crel ----
  float4 c1 = *(const float4*)(Cq + (size_t)(b * 49 + q) * 256 + d4);
  float4 c2 = *(const float4*)(Ck + (size_t)(b * 49 + kk) * 256 + d4);
  float z0 = c1.x + c2.x, z1 = c1.y + c2.y, z2 = c1.z + c2.z, z3 = c1.w + c2.w;
  float s = wsum(z0 + z1 + z2 + z3);
  float ss = wsum(z0 * z0 + z1 * z1 + z2 * z2 + z3 * z3);
  float mC = s * (1.f / 256.f);
  float rsC = rsqrtf(ss * (1.f / 256.f) - mC * mC + EPSV);
  float4 g4 = *(const float4*)&sgc[d4];
  float4 b4 = *(const float4*)&sbc[d4];
  float h0 = fmaxf((z0 - mC) * rsC * g4.x + b4.x, 0.f);
  float h1 = fmaxf((z1 - mC) * rsC * g4.y + b4.y, 0.f);
  float h2 = fmaxf((z2 - mC) * rsC * g4.z + b4.z, 0.f);
  float h3 = fmaxf((z3 - mC) * rsC * g4.w + b4.w, 0.f);
  float lg[14];
#pragma unroll
  for (int r = 0; r < 14; r++) {
    float4 w4 = *(const float4*)&sW[r * 256 + d4];
    float lp = h0 * w4.x + h1 * w4.y + h2 * w4.z + h3 * w4.w;
    lg[r] = wsum(lp) + sb2[r];
  }
  float mx = lg[0];
#pragma unroll
  for (int r = 1; r < 14; r++) mx = fmaxf(mx, lg[r]);
  float se = 0.f, sc = 0.f;
#pragma unroll
  for (int r = 0; r < 14; r++) {
    float e = __expf(lg[r] - mx);
    se += e;
    sc += e * scl[r];
  }
  float s1 = sc / (se * (1.f + 1e-8f));

  // ---- relation branch: 512-d LN -> relu -> dot wrg ----
  const float* rqb = Rq + (size_t)(b * 49 + q) * 512;
  const float* rkb = Rk + (size_t)(b * 49 + kk) * 512;
  float4 a0 = *(const float4*)(rqb + d4);
  float4 a1 = *(const float4*)(rqb + 256 + d4);
  float4 k0v = *(const float4*)(rkb + d4);
  float4 k1v = *(const float4*)(rkb + 256 + d4);
  float y0 = a0.x + k0v.x, y1 = a0.y + k0v.y, y2 = a0.z + k0v.z, y3 = a0.w + k0v.w;
  float y4 = a1.x + k1v.x, y5 = a1.y + k1v.y, y6 = a1.z + k1v.z, y7 = a1.w + k1v.w;
  float sR = wsum(y0 + y1 + y2 + y3 + y4 + y5 + y6 + y7);
  float ssR = wsum(y0 * y0 + y1 * y1 + y2 * y2 + y3 * y3 + y4 * y4 + y5 * y5 +
                   y6 * y6 + y7 * y7);
  float mR = sR * (1.f / 512.f);
  float rsR = rsqrtf(ssR * (1.f / 512.f) - mR * mR + EPSV);
  float4 gr0 = *(const float4*)&sgr[d4];
  float4 gr1 = *(const float4*)&sgr[256 + d4];
  float4 br0 = *(const float4*)&sbr[d4];
  float4 br1v = *(const float4*)&sbr[256 + d4];
  float4 wg0 = *(const float4*)&swg[d4];
  float4 wg1 = *(const float4*)&swg[256 + d4];
  float s2p = 0.f;
  s2p += fmaxf((y0 - mR) * rsR * gr0.x + br0.x, 0.f) * wg0.x;
  s2p += fmaxf((y1 - mR) * rsR * gr0.y + br0.y, 0.f) * wg0.y;
  s2p += fmaxf((y2 - mR) * rsR * gr0.z + br0.z, 0.f) * wg0.z;
  s2p += fmaxf((y3 - mR) * rsR * gr0.w + br0.w, 0.f) * wg0.w;
  s2p += fmaxf((y4 - mR) * rsR * gr1.x + br1v.x, 0.f) * wg1.x;
  s2p += fmaxf((y5 - mR) * rsR * gr1.y + br1v.y, 0.f) * wg1.y;
  s2p += fmaxf((y6 - mR) * rsR * gr1.z + br1v.z, 0.f) * wg1.z;
  s2p += fmaxf((y7 - mR) * rsR * gr1.w + br1v.w, 0.f) * wg1.w;
  float s2 = wsum(s2p);

  float gin = s1 + s2 + cconst;
  float gate = 1.f / (1.f + __expf(-gin));
  if (lane == 0) gfac[pid] = 1.f + gate;
}

// ---------- K6: gated softmax attention, one block per (b,h) ----------
__global__ __launch_bounds__(256) void attn(const float* __restrict__ qb,
                                            const float* __restrict__ kb,
                                            const float* __restrict__ vb,
                                            const float* __restrict__ gfac,
                                            float* __restrict__ ao) {
  int b = blockIdx.x >> 3, h = blockIdx.x & 7;
  __shared__ float Kh[64][65];  // rows 49..63 uninitialized, masked out below
  __shared__ float Vh[49][65];
  __shared__ float G[2401];
  int tid = threadIdx.x;
  for (int i = tid; i < 49 * 64; i += 256) {
    int k = i >> 6, d = i & 63;
    size_t off = (((size_t)(b * 49 + k)) << 9) + h * 64 + d;
    Kh[k][d] = kb[off];
    Vh[k][d] = vb[off];
  }
  for (int i = tid; i < 2401; i += 256) G[i] = gfac[b * 2401 + i];
  __syncthreads();
  int wave = tid >> 6, lane = tid & 63;
  for (int q = wave; q < 49; q += 4) {
    float qv = qb[(((size_t)(b * 49 + q)) << 9) + h * 64 + lane];
    float dot = 0.f;
#pragma unroll
    for (int d = 0; d < 64; d++) dot += __shfl(qv, d, 64) * Kh[lane][d];
    float enh = (lane < 49) ? dot * SCALEC * G[q * 49 + lane] : -1e30f;
    float mxv = wmax(enh);
    float e = (lane < 49) ? __expf(enh - mxv) : 0.f;
    float ssum = wsum(e);
    float w = e / ssum;
    float out = 0.f;
#pragma unroll
    for (int k = 0; k < 49; k++) out += __shfl(w, k, 64) * Vh[k][lane];
    ao[(((size_t)(b * 49 + q)) << 9) + h * 64 + lane] = out;
  }
}

// ---------- launch ----------
extern "C" void kernel_launch(void* const* d_in, const int* in_sizes, int n_in,
                              void* d_out, int out_size, void* d_ws, size_t ws_size,
                              hipStream_t stream) {
  const float* queries = (const float*)d_in[0];
  const float* keys = (const float*)d_in[1];
  const float* values = (const float*)d_in[2];
  const float* Wq = (const float*)d_in[3];
  const float* bq = (const float*)d_in[4];
  const float* Wk = (const float*)d_in[5];
  const float* bk = (const float*)d_in[6];
  const float* Wv = (const float*)d_in[7];
  const float* bv = (const float*)d_in[8];
  const float* Wo = (const float*)d_in[9];
  const float* bo = (const float*)d_in[10];
  const float* rel_embed = (const float*)d_in[11];
  const float* Wproj = (const float*)d_in[12];
  const float* bproj = (const float*)d_in[13];
  const float* Wgate = (const float*)d_in[14];
  const float* bgate = (const float*)d_in[15];
  const float* Wc1 = (const float*)d_in[16];
  const float* bc1 = (const float*)d_in[17];
  const float* gc = (const float*)d_in[18];
  const float* bcln = (const float*)d_in[19];
  const float* Wc2 = (const float*)d_in[20];
  const float* bc2 = (const float*)d_in[21];
  const float* Wr1 = (const float*)d_in[22];
  const float* br1 = (const float*)d_in[23];
  const float* gr = (const float*)d_in[24];
  const float* brln = (const float*)d_in[25];
  const float* Wr2 = (const float*)d_in[26];
  const float* br2 = (const float*)d_in[27];
  const float* convW = (const float*)d_in[28];
  const float* convb = (const float*)d_in[29];

  float* W = (float*)d_ws;
  float* Wt = W + 0;             // 2359296
  float* hbuf = W + 2359296;     // 802816
  float* eq = W + 3162112;
  float* ek = W + 3964928;
  float* ev = W + 4767744;
  float* qbuf = W + 5570560;
  float* kbuf = W + 6373376;
  float* vbuf = W + 7176192;
  float* Cqw = W + 7979008;      // 401408
  float* Ckw = W + 8380416;      // 401408
  float* Rqw = W + 8781824;      // 802816
  float* Rkw = W + 9584640;      // 802816
  float* ao = W + 10387456;      // 802816
  float* gf = W + 11190272;      // 76832
  float* mu = W + 11267104;      // 512
  float* rsg = W + 11267616;     // 512
  float* crel = W + 11268128;    // 16
  float* wrg = W + 11268144;     // 512
  float* ccst = W + 11268656;    // 16   -> total 11268672 floats ~= 45.1 MB

  hipLaunchKernelGGL(transposeW, dim3(1024), dim3(256), 0, stream, convW, Wt);
  hipLaunchKernelGGL(smalls_kernel, dim3(3), dim3(256), 0, stream, Wproj, Wgate,
                     rel_embed, bproj, br2, bgate, Wr2, crel, wrg, ccst);
  hipLaunchKernelGGL(conv_gemm, dim3(8, 25), dim3(256), 0, stream, queries, Wt,
                     convb, hbuf);
  hipLaunchKernelGGL(bn_stats, dim3(512), dim3(256), 0, stream, hbuf, mu, rsg);
  hipLaunchKernelGGL(fuse_xs, dim3(3136), dim3(256), 0, stream, hbuf, mu, rsg,
                     queries, keys, values, eq, ek, ev);

  GemmJobs jobs;
  jobs.A[0] = eq; jobs.Bm[0] = Wq; jobs.bias[0] = bq; jobs.C[0] = qbuf; jobs.N[0] = 512;
  jobs.A[1] = ek; jobs.Bm[1] = Wk; jobs.bias[1] = bk; jobs.C[1] = kbuf; jobs.N[1] = 512;
  jobs.A[2] = ev; jobs.Bm[2] = Wv; jobs.bias[2] = bv; jobs.C[2] = vbuf; jobs.N[2] = 512;
  jobs.A[3] = eq; jobs.Bm[3] = Wc1; jobs.bias[3] = bc1; jobs.C[3] = Cqw; jobs.N[3] = 256;
  jobs.A[4] = ek; jobs.Bm[4] = Wc1 + 512 * 256; jobs.bias[4] = nullptr; jobs.C[4] = Ckw; jobs.N[4] = 256;
  jobs.A[5] = eq; jobs.Bm[5] = Wr1; jobs.bias[5] = br1; jobs.C[5] = Rqw; jobs.N[5] = 512;
  jobs.A[6] = ek; jobs.Bm[6] = Wr1 + 512 * 512; jobs.bias[6] = nullptr; jobs.C[6] = Rkw; jobs.N[6] = 512;
  hipLaunchKernelGGL(gemm_multi, dim3(8, 25, 7), dim3(256), 0, stream, jobs,
                     Mrows, 512);

  hipLaunchKernelGGL(pair_gate, dim3(19208), dim3(256), 0, stream, Cqw, Ckw, Rqw,
                     Rkw, Wc2, bc2, gc, bcln, gr, brln, crel, wrg, ccst, gf);
  hipLaunchKernelGGL(attn, dim3(256), dim3(256), 0, stream, qbuf, kbuf, vbuf, gf, ao);

  GemmJobs j2;
  j2.A[0] = ao; j2.Bm[0] = Wo; j2.bias[0] = bo; j2.C[0] = (float*)d_out; j2.N[0] = 512;
  for (int z = 1; z < 7; z++) { j2.A[z] = nullptr; j2.Bm[z] = nullptr; j2.bias[z] = nullptr; j2.C[z] = nullptr; j2.N[z] = 0; }
  hipLaunchKernelGGL(gemm_multi, dim3(8, 25, 1), dim3(256), 0, stream, j2, Mrows, 512);
}

// Round 2
// 408.957 us; speedup vs baseline: 1.7956x; 1.7956x over previous
//
#include <hip/hip_runtime.h>
#include <math.h>

typedef _Float16 f16;
typedef _Float16 f16x8 __attribute__((ext_vector_type(8)));
typedef float f32x4 __attribute__((ext_vector_type(4)));

static constexpr int Mrows = 1568;   // 32*49
static constexpr float SCALEC = 0.125f;
#define EPSV 1e-5f

// ---------- helpers ----------
__device__ inline float wsum(float v) {
#pragma unroll
  for (int m = 32; m >= 1; m >>= 1) v += __shfl_xor(v, m, 64);
  return v;
}
__device__ inline float wmax(float v) {
#pragma unroll
  for (int m = 32; m >= 1; m >>= 1) v = fmaxf(v, __shfl_xor(v, m, 64));
  return v;
}
// async global->LDS, 16B per lane; dst must be wave-uniform base (lane*16 added by HW)
__device__ inline void gld16(const void* g, void* l) {
  __builtin_amdgcn_global_load_lds((const __attribute__((address_space(1))) void*)g,
                                   (__attribute__((address_space(3))) void*)l, 16, 0, 0);
}

// ---------- prep: zero h | build padded Qp (f16) | convW -> Wtb [o][t*512+c] f16 ----------
__global__ __launch_bounds__(256) void prep(const float* __restrict__ queries,
                                            const float* __restrict__ convW,
                                            float* __restrict__ h,
                                            f16* __restrict__ Qp,
                                            f16* __restrict__ Wtb) {
  int bx = blockIdx.x;
  int tid = threadIdx.x;
  if (bx < 784) {  // zero h: 802816 floats = 784*256 float4
    ((float4*)h)[bx * 256 + tid] = make_float4(0.f, 0.f, 0.f, 0.f);
  } else if (bx < 784 + 5184) {  // Qp: 32*81*512 f16
    int idx = (bx - 784) * 256 + tid;
    int c = idx & 511;
    int iijj = (idx >> 9) % 81;
    int b = idx / (81 * 512);
    int ii = iijj / 9, jj = iijj % 9;
    float v = 0.f;
    if (ii >= 1 && ii <= 7 && jj >= 1 && jj <= 7)
      v = queries[(((size_t)(b * 49 + (ii - 1) * 7 + (jj - 1))) << 9) + c];
    Qp[idx] = (f16)v;
  } else {  // Wtb: 512x512 (o,c), 9 taps each
    int idx = (bx - 5968) * 256 + tid;
    int o = idx >> 9, c = idx & 511;
    const float* s = convW + (size_t)o * 4608 + c * 9;
    f16* d = Wtb + (size_t)o * 4608 + c;
#pragma unroll
    for (int t = 0; t < 9; t++) d[t * 512] = (f16)s[t];
  }
}

// ---------- small precomputes: crel[14], wrg[512], cconst ----------
__global__ __launch_bounds__(256) void smalls_kernel(
    const float* __restrict__ Wproj, const float* __restrict__ Wgate,
    const float* __restrict__ rel_embed, const float* __restrict__ bproj,
    const float* __restrict__ br2, const float* __restrict__ bgate,
    const float* __restrict__ Wr2, float* __restrict__ crel,
    float* __restrict__ wrg, float* __restrict__ cconst) {
  int tid = threadIdx.x;
  if (blockIdx.x == 0) {
    __shared__ float pg[64];
    if (tid < 64) {
      float s = 0.f;
      for (int d = 0; d < 512; d++) s += Wproj[tid * 512 + d] * Wgate[d];
      pg[tid] = s;
    }
    __syncthreads();
    if (tid < 14) {
      float s = 0.f;
      for (int dk = 0; dk < 64; dk++) s += rel_embed[tid * 64 + dk] * pg[dk];
      crel[tid] = s;
    }
    if (tid == 64) {
      float s = 0.f;
      for (int d = 0; d < 512; d++) s += (bproj[d] + br2[d]) * Wgate[d];
      cconst[0] = s + bgate[0];
    }
  } else {
    int d = (blockIdx.x - 1) * 256 + tid;
    float s = 0.f;
    for (int d2 = 0; d2 < 512; d2++) s += Wr2[(size_t)d * 512 + d2] * Wgate[d2];
    wrg[d] = s;
  }
}

// ---------- tiled transpose+convert: dst[n][k] = (f16)src[k][n], rows(K)=512 ----------
struct TJobs { const float* src[8]; f16* dst[8]; int cols[8]; };
__global__ __launch_bounds__(256) void transpose_w(TJobs tj) {
  int z = blockIdx.z;
  int cols = tj.cols[z];
  int n0 = blockIdx.x * 32;
  if (n0 >= cols) return;
  int k0 = blockIdx.y * 32;
  const float* src = tj.src[z];
  f16* dst = tj.dst[z];
  __shared__ float tile[32][33];
  int tid = threadIdx.x;
  int c = tid & 31, r0 = tid >> 5;
#pragma unroll
  for (int i = 0; i < 4; i++) {
    int r = r0 + i * 8;
    tile[r][c] = src[(size_t)(k0 + r) * cols + n0 + c];
  }
  __syncthreads();
#pragma unroll
  for (int i = 0; i < 4; i++) {
    int r = r0 + i * 8;
    dst[(size_t)(n0 + r) * 512 + k0 + c] = (f16)tile[c][r];
  }
}

// ---------- conv as implicit-im2col MFMA GEMM, split-K=8, atomicAdd into h ----------
// A[m][k]: m=(b,p), k=t*512+c -> Qp[b][pi+ti][pj+tj][c];  B^T = Wtb [o=512][K=4608]
__global__ __launch_bounds__(256) void conv_mfma(const f16* __restrict__ Qp,
                                                 const f16* __restrict__ Wtb,
                                                 float* __restrict__ h) {
  __shared__ f16 As2[2048];  // [slice4][kq4][m16][8]
  __shared__ f16 Bs2[2048];
  int tid = threadIdx.x;
  int n0 = blockIdx.x * 64;
  int m0 = blockIdx.y * 64;
  int kb = blockIdx.z * 576;
  int lane = tid & 63, wv = tid >> 6;
  int kq = (tid >> 4) & 3, mm = tid & 15;
  int rowA = m0 + wv * 16 + mm;
  if (rowA > Mrows - 1) rowA = Mrows - 1;
  int b = rowA / 49, p = rowA % 49;
  int pi = p / 7, pj = p % 7;
  const f16* qbase = Qp + (size_t)b * 81 * 512 + kq * 8;
  int rowB = n0 + wv * 16 + mm;
  const f16* bSrc = Wtb + (size_t)rowB * 4608 + kq * 8 + kb;
  f16* aDst = &As2[wv * 512];
  f16* bDst = &Bs2[wv * 512];
  f32x4 acc[4];
#pragma unroll
  for (int i = 0; i < 4; i++) acc[i] = (f32x4){0.f, 0.f, 0.f, 0.f};
  for (int s = 0; s < 18; s++) {
    int k0 = kb + s * 32;
    int t = k0 >> 9, c0 = k0 & 511;
    int ti = t / 3, tj = t - ti * 3;
    const f16* aSrc = qbase + (size_t)((pi + ti) * 9 + (pj + tj)) * 512 + c0;
    gld16(aSrc, aDst);
    gld16(bSrc + s * 32, bDst);
    __syncthreads();
    f16x8 a = *(const f16x8*)&As2[(wv << 9) + (lane << 3)];
#pragma unroll
    for (int nb = 0; nb < 4; nb++) {
      f16x8 bf = *(const f16x8*)&Bs2[(nb << 9) + (lane << 3)];
      acc[nb] = __builtin_amdgcn_mfma_f32_16x16x32_f16(a, bf, acc[nb], 0, 0, 0);
    }
    __syncthreads();
  }
  int r0 = m0 + wv * 16 + ((lane >> 4) << 2);
  int cw = lane & 15;
#pragma unroll
  for (int nb = 0; nb < 4; nb++) {
    int col = n0 + nb * 16 + cw;
#pragma unroll
    for (int r = 0; r < 4; r++) {
      int row = r0 + r;
      if (row < Mrows) atomicAdd(&h[(size_t)row * 512 + col], acc[nb][r]);
    }
  }
}

// ---------- BatchNorm stats per channel ----------
__global__ __launch_bounds__(256) void bn_stats(const float* __restrict__ h,
                                                float* __restrict__ mu,
                                                float* __restrict__ rsg) {
  int c = blockIdx.x;
  int tid = threadIdx.x;
  float s = 0.f, ss = 0.f;
  for (int r = tid; r < Mrows; r += 256) {
    float v = h[(size_t)r * 512 + c];
    s += v;
    ss += v * v;
  }
  s = wsum(s);
  ss = wsum(ss);
  __shared__ float r1[4], r2[4];
  int wave = tid >> 6, lane = tid & 63;
  if (lane == 0) { r1[wave] = s; r2[wave] = ss; }
  __syncthreads();
  if (tid == 0) {
    float S = r1[0] + r1[1] + r1[2] + r1[3];
    float SS = r2[0] + r2[1] + r2[2] + r2[3];
    float m = S / (float)Mrows;
    float var = SS / (float)Mrows - m * m;
    mu[c] = m;
    rsg[c] = rsqrtf(var + EPSV);
  }
}

// ---------- xs = relu(bn(h)); eq/ek/ev (f16) ----------
__global__ __launch_bounds__(256) void fuse_xs(
    const float* __restrict__ h, const float* __restrict__ mu,
    const float* __restrict__ rsg, const float* __restrict__ Q,
    const float* __restrict__ Kin, const float* __restrict__ Vin,
    f16* __restrict__ eqh, f16* __restrict__ ekh, f16* __restrict__ evh) {
  int i = blockIdx.x * 256 + threadIdx.x;
  int c = i & 511;
  float xs = fmaxf((h[i] - mu[c]) * rsg[c], 0.f);
  eqh[i] = (f16)(xs + Q[i]);
  ekh[i] = (f16)(xs + Kin[i]);
  evh[i] = (f16)(xs + Vin[i]);
}

// ---------- generic MFMA GEMM: C[z] = A[z](f16,[M][512]) @ BT[z]^T (+bias), fp32 out ----------
struct MJobs { const f16* A[7]; const f16* BT[7]; const float* bias[7]; float* C[7]; int N[7]; };
__global__ __launch_bounds__(256) void gemm_mf(MJobs jb) {
  int z = blockIdx.z;
  int N = jb.N[z];
  int n0 = blockIdx.x * 64;
  if (n0 >= N) return;
  int m0 = blockIdx.y * 64;
  const f16* A = jb.A[z];
  const f16* BT = jb.BT[z];
  __shared__ f16 As2[2048];
  __shared__ f16 Bs2[2048];
  int tid = threadIdx.x, lane = tid & 63, wv = tid >> 6;
  int kq = (tid >> 4) & 3, mm = tid & 15;
  int rowA = m0 + wv * 16 + mm;
  if (rowA > Mrows - 1) rowA = Mrows - 1;
  const f16* aSrc = A + (size_t)rowA * 512 + kq * 8;
  int rowB = n0 + wv * 16 + mm;
  const f16* bSrc = BT + (size_t)rowB * 512 + kq * 8;
  f16* aDst = &As2[wv * 512];
  f16* bDst = &Bs2[wv * 512];
  f32x4 acc[4];
#pragma unroll
  for (int i = 0; i < 4; i++) acc[i] = (f32x4){0.f, 0.f, 0.f, 0.f};
  for (int s = 0; s < 16; s++) {
    gld16(aSrc + s * 32, aDst);
    gld16(bSrc + s * 32, bDst);
    __syncthreads();
    f16x8 a = *(const f16x8*)&As2[(wv << 9) + (lane << 3)];
#pragma unroll
    for (int nb = 0; nb < 4; nb++) {
      f16x8 bf = *(const f16x8*)&Bs2[(nb << 9) + (lane << 3)];
      acc[nb] = __builtin_amdgcn_mfma_f32_16x16x32_f16(a, bf, acc[nb], 0, 0, 0);
    }
    __syncthreads();
  }
  const float* bias = jb.bias[z];
  float* C = jb.C[z];
  int r0 = m0 + wv * 16 + ((lane >> 4) << 2);
  int cw = lane & 15;
#pragma unroll
  for (int nb = 0; nb < 4; nb++) {
    int col = n0 + nb * 16 + cw;
    float bv = bias ? bias[col] : 0.f;
#pragma unroll
    for (int r = 0; r < 4; r++) {
      int row = r0 + r;
      if (row < Mrows) C[(size_t)row * N + col] = acc[nb][r] + bv;
    }
  }
}

// ---------- per-pair gate factor (1 + sigmoid(...)), one wave per pair ----------
__global__ __launch_bounds__(256) void pair_gate(
    const float* __restrict__ Cq, const float* __restrict__ Ck,
    const float* __restrict__ Rq, const float* __restrict__ Rk,
    const float* __restrict__ Wc2, const float* __restrict__ bc2,
    const float* __restrict__ gc, const float* __restrict__ bcln,
    const float* __restrict__ gr, const float* __restrict__ brln,
    const float* __restrict__ crel, const float* __restrict__ wrg,
    const float* __restrict__ cconstp, float* __restrict__ gfac) {
  __shared__ float sW[14 * 256];
  __shared__ float sgc[256], sbc[256];
  __shared__ float sgr[512], sbr[512], swg[512];
  __shared__ float scl[14], sb2[14];
  int tid = threadIdx.x;
  for (int i = tid; i < 14 * 256; i += 256) {
    int r = i >> 8, d = i & 255;
    sW[i] = Wc2[d * 14 + r];
  }
  sgc[tid] = gc[tid];
  sbc[tid] = bcln[tid];
  sgr[tid] = gr[tid]; sgr[tid + 256] = gr[tid + 256];
  sbr[tid] = brln[tid]; sbr[tid + 256] = brln[tid + 256];
  swg[tid] = wrg[tid]; swg[tid + 256] = wrg[tid + 256];
  if (tid < 14) { scl[tid] = crel[tid]; sb2[tid] = bc2[tid]; }
  __syncthreads();
  float cconst = cconstp[0];
  int wave = tid >> 6, lane = tid & 63;
  int pid = blockIdx.x * 4 + wave;
  int b = pid / 2401;
  int r2 = pid % 2401;
  int q = r2 / 49, kk = r2 % 49;
  int d4 = lane * 4;

  float4 c1 = *(const float4*)(Cq + (size_t)(b * 49 + q) * 256 + d4);
  float4 c2 = *(const float4*)(Ck + (size_t)(b * 49 + kk) * 256 + d4);
  float z0 = c1.x + c2.x, z1 = c1.y + c2.y, z2 = c1.z + c2.z, z3 = c1.w + c2.w;
  float s = wsum(z0 + z1 + z2 + z3);
  float ss = wsum(z0 * z0 + z1 * z1 + z2 * z2 + z3 * z3);
  float mC = s * (1.f / 256.f);
  float rsC = rsqrtf(ss * (1.f / 256.f) - mC * mC + EPSV);
  float4 g4 = *(const float4*)&sgc[d4];
  float4 b4 = *(const float4*)&sbc[d4];
  float h0 = fmaxf((z0 - mC) * rsC * g4.x + b4.x, 0.f);
  float h1 = fmaxf((z1 - mC) * rsC * g4.y + b4.y, 0.f);
  float h2 = fmaxf((z2 - mC) * rsC * g4.z + b4.z, 0.f);
  float h3 = fmaxf((z3 - mC) * rsC * g4.w + b4.w, 0.f);
  float lg[14];
#pragma unroll
  for (int r = 0; r < 14; r++) {
    float4 w4 = *(const float4*)&sW[r * 256 + d4];
    float lp = h0 * w4.x + h1 * w4.y + h2 * w4.z + h3 * w4.w;
    lg[r] = wsum(lp) + sb2[r];
  }
  float mx = lg[0];
#pragma unroll
  for (int r = 1; r < 14; r++) mx = fmaxf(mx, lg[r]);
  float se = 0.f, sc = 0.f;
#pragma unroll
  for (int r = 0; r < 14; r++) {
    float e = __expf(lg[r] - mx);
    se += e;
    sc += e * scl[r];
  }
  float s1 = sc / (se * (1.f + 1e-8f));

  const float* rqb = Rq + (size_t)(b * 49 + q) * 512;
  const float* rkb = Rk + (size_t)(b * 49 + kk) * 512;
  float4 a0 = *(const float4*)(rqb + d4);
  float4 a1 = *(const float4*)(rqb + 256 + d4);
  float4 k0v = *(const float4*)(rkb + d4);
  float4 k1v = *(const float4*)(rkb + 256 + d4);
  float y0 = a0.x + k0v.x, y1 = a0.y + k0v.y, y2 = a0.z + k0v.z, y3 = a0.w + k0v.w;
  float y4 = a1.x + k1v.x, y5 = a1.y + k1v.y, y6 = a1.z + k1v.z, y7 = a1.w + k1v.w;
  float sR = wsum(y0 + y1 + y2 + y3 + y4 + y5 + y6 + y7);
  float ssR = wsum(y0 * y0 + y1 * y1 + y2 * y2 + y3 * y3 + y4 * y4 + y5 * y5 +
                   y6 * y6 + y7 * y7);
  float mR = sR * (1.f / 512.f);
  float rsR = rsqrtf(ssR * (1.f / 512.f) - mR * mR + EPSV);
  float4 gr0 = *(const float4*)&sgr[d4];
  float4 gr1 = *(const float4*)&sgr[256 + d4];
  float4 br0 = *(const float4*)&sbr[d4];
  float4 br1v = *(const float4*)&sbr[256 + d4];
  float4 wg0 = *(const float4*)&swg[d4];
  float4 wg1 = *(const float4*)&swg[256 + d4];
  float s2p = 0.f;
  s2p += fmaxf((y0 - mR) * rsR * gr0.x + br0.x, 0.f) * wg0.x;
  s2p += fmaxf((y1 - mR) * rsR * gr0.y + br0.y, 0.f) * wg0.y;
  s2p += fmaxf((y2 - mR) * rsR * gr0.z + br0.z, 0.f) * wg0.z;
  s2p += fmaxf((y3 - mR) * rsR * gr0.w + br0.w, 0.f) * wg0.w;
  s2p += fmaxf((y4 - mR) * rsR * gr1.x + br1v.x, 0.f) * wg1.x;
  s2p += fmaxf((y5 - mR) * rsR * gr1.y + br1v.y, 0.f) * wg1.y;
  s2p += fmaxf((y6 - mR) * rsR * gr1.z + br1v.z, 0.f) * wg1.z;
  s2p += fmaxf((y7 - mR) * rsR * gr1.w + br1v.w, 0.f) * wg1.w;
  float s2 = wsum(s2p);

  float gin = s1 + s2 + cconst;
  float gate = 1.f / (1.f + __expf(-gin));
  if (lane == 0) gfac[pid] = 1.f + gate;
}

// ---------- gated softmax attention, one block per (b,h); ao in f16 ----------
__global__ __launch_bounds__(256) void attn(const float* __restrict__ qb,
                                            const float* __restrict__ kb,
                                            const float* __restrict__ vb,
                                            const float* __restrict__ gfac,
                                            f16* __restrict__ aoh) {
  int b = blockIdx.x >> 3, h = blockIdx.x & 7;
  __shared__ float Kh[64][65];
  __shared__ float Vh[49][65];
  __shared__ float G[2401];
  int tid = threadIdx.x;
  for (int i = tid; i < 49 * 64; i += 256) {
    int k = i >> 6, d = i & 63;
    size_t off = (((size_t)(b * 49 + k)) << 9) + h * 64 + d;
    Kh[k][d] = kb[off];
    Vh[k][d] = vb[off];
  }
  for (int i = tid; i < 2401; i += 256) G[i] = gfac[b * 2401 + i];
  __syncthreads();
  int wave = tid >> 6, lane = tid & 63;
  for (int q = wave; q < 49; q += 4) {
    float qv = qb[(((size_t)(b * 49 + q)) << 9) + h * 64 + lane];
    float dot = 0.f;
#pragma unroll
    for (int d = 0; d < 64; d++) dot += __shfl(qv, d, 64) * Kh[lane][d];
    float enh = (lane < 49) ? dot * SCALEC * G[q * 49 + lane] : -1e30f;
    float mxv = wmax(enh);
    float e = (lane < 49) ? __expf(enh - mxv) : 0.f;
    float ssum = wsum(e);
    float w = e / ssum;
    float out = 0.f;
#pragma unroll
    for (int k = 0; k < 49; k++) out += __shfl(w, k, 64) * Vh[k][lane];
    aoh[(((size_t)(b * 49 + q)) << 9) + h * 64 + lane] = (f16)out;
  }
}

// ---------- launch ----------
extern "C" void kernel_launch(void* const* d_in, const int* in_sizes, int n_in,
                              void* d_out, int out_size, void* d_ws, size_t ws_size,
                              hipStream_t stream) {
  const float* queries = (const float*)d_in[0];
  const float* keys = (const float*)d_in[1];
  const float* values = (const float*)d_in[2];
  const float* Wq = (const float*)d_in[3];
  const float* bq = (const float*)d_in[4];
  const float* Wk = (const float*)d_in[5];
  const float* bk = (const float*)d_in[6];
  const float* Wv = (const float*)d_in[7];
  const float* bv = (const float*)d_in[8];
  const float* Wo = (const float*)d_in[9];
  const float* bo = (const float*)d_in[10];
  const float* rel_embed = (const float*)d_in[11];
  const float* Wproj = (const float*)d_in[12];
  const float* bproj = (const float*)d_in[13];
  const float* Wgate = (const float*)d_in[14];
  const float* bgate = (const float*)d_in[15];
  const float* Wc1 = (const float*)d_in[16];
  const float* bc1 = (const float*)d_in[17];
  const float* gc = (const float*)d_in[18];
  const float* bcln = (const float*)d_in[19];
  const float* Wc2 = (const float*)d_in[20];
  const float* bc2 = (const float*)d_in[21];
  const float* Wr1 = (const float*)d_in[22];
  const float* br1 = (const float*)d_in[23];
  const float* gr = (const float*)d_in[24];
  const float* brln = (const float*)d_in[25];
  const float* Wr2 = (const float*)d_in[26];
  const float* br2 = (const float*)d_in[27];
  const float* convW = (const float*)d_in[28];
  // d_in[29] = convb: exactly cancelled by BatchNorm(affine=False) -> unused

  float* W = (float*)d_ws;
  size_t o = 0;
  f16* Qp = (f16*)(W + o); o += 663552;       // 32*81*512 f16
  f16* Wtb = (f16*)(W + o); o += 1179648;     // 512*4608 f16
  f16* WqT = (f16*)(W + o); o += 131072;
  f16* WkT = (f16*)(W + o); o += 131072;
  f16* WvT = (f16*)(W + o); o += 131072;
  f16* WoT = (f16*)(W + o); o += 131072;
  f16* Wc1aT = (f16*)(W + o); o += 65536;
  f16* Wc1bT = (f16*)(W + o); o += 65536;
  f16* Wr1aT = (f16*)(W + o); o += 131072;
  f16* Wr1bT = (f16*)(W + o); o += 131072;
  float* hbuf = W + o; o += 802816;
  f16* eqh = (f16*)(W + o); o += 401408;
  f16* ekh = (f16*)(W + o); o += 401408;
  f16* evh = (f16*)(W + o); o += 401408;
  float* qbuf = W + o; o += 802816;
  float* kbuf = W + o; o += 802816;
  float* vbuf = W + o; o += 802816;
  float* Cqw = W + o; o += 401408;
  float* Ckw = W + o; o += 401408;
  float* Rqw = W + o; o += 802816;
  float* Rkw = W + o; o += 802816;
  f16* aoh = (f16*)(W + o); o += 200704;
  float* gf = W + o; o += 76832;
  float* mu = W + o; o += 512;
  float* rsg = W + o; o += 512;
  float* crel = W + o; o += 16;
  float* wrg = W + o; o += 512;
  float* ccst = W + o; o += 16;

  hipLaunchKernelGGL(prep, dim3(784 + 5184 + 1024), dim3(256), 0, stream,
                     queries, convW, hbuf, Qp, Wtb);
  hipLaunchKernelGGL(smalls_kernel, dim3(3), dim3(256), 0, stream, Wproj, Wgate,
                     rel_embed, bproj, br2, bgate, Wr2, crel, wrg, ccst);

  TJobs tj;
  tj.src[0] = Wq;  tj.dst[0] = WqT;  tj.cols[0] = 512;
  tj.src[1] = Wk;  tj.dst[1] = WkT;  tj.cols[1] = 512;
  tj.src[2] = Wv;  tj.dst[2] = WvT;  tj.cols[2] = 512;
  tj.src[3] = Wo;  tj.dst[3] = WoT;  tj.cols[3] = 512;
  tj.src[4] = Wc1;             tj.dst[4] = Wc1aT; tj.cols[4] = 256;
  tj.src[5] = Wc1 + 512 * 256; tj.dst[5] = Wc1bT; tj.cols[5] = 256;
  tj.src[6] = Wr1;             tj.dst[6] = Wr1aT; tj.cols[6] = 512;
  tj.src[7] = Wr1 + 512 * 512; tj.dst[7] = Wr1bT; tj.cols[7] = 512;
  hipLaunchKernelGGL(transpose_w, dim3(16, 16, 8), dim3(256), 0, stream, tj);

  hipLaunchKernelGGL(conv_mfma, dim3(8, 25, 8), dim3(256), 0, stream, Qp, Wtb, hbuf);
  hipLaunchKernelGGL(bn_stats, dim3(512), dim3(256), 0, stream, hbuf, mu, rsg);
  hipLaunchKernelGGL(fuse_xs, dim3(3136), dim3(256), 0, stream, hbuf, mu, rsg,
                     queries, keys, values, eqh, ekh, evh);

  MJobs jb;
  jb.A[0] = eqh; jb.BT[0] = WqT;   jb.bias[0] = bq;      jb.C[0] = qbuf; jb.N[0] = 512;
  jb.A[1] = ekh; jb.BT[1] = WkT;   jb.bias[1] = bk;      jb.C[1] = kbuf; jb.N[1] = 512;
  jb.A[2] = evh; jb.BT[2] = WvT;   jb.bias[2] = bv;      jb.C[2] = vbuf; jb.N[2] = 512;
  jb.A[3] = eqh; jb.BT[3] = Wc1aT; jb.bias[3] = bc1;     jb.C[3] = Cqw;  jb.N[3] = 256;
  jb.A[4] = ekh; jb.BT[4] = Wc1bT; jb.bias[4] = nullptr; jb.C[4] = Ckw;  jb.N[4] = 256;
  jb.A[5] = eqh; jb.BT[5] = Wr1aT; jb.bias[5] = br1;     jb.C[5] = Rqw;  jb.N[5] = 512;
  jb.A[6] = ekh; jb.BT[6] = Wr1bT; jb.bias[6] = nullptr; jb.C[6] = Rkw;  jb.N[6] = 512;
  hipLaunchKernelGGL(gemm_mf, dim3(8, 25, 7), dim3(256), 0, stream, jb);

  hipLaunchKernelGGL(pair_gate, dim3(19208), dim3(256), 0, stream, Cqw, Ckw, Rqw,
                     Rkw, Wc2, bc2, gc, bcln, gr, brln, crel, wrg, ccst, gf);
  hipLaunchKernelGGL(attn, dim3(256), dim3(256), 0, stream, qbuf, kbuf, vbuf, gf, aoh);

  MJobs j2;
  j2.A[0] = aoh; j2.BT[0] = WoT; j2.bias[0] = bo; j2.C[0] = (float*)d_out; j2.N[0] = 512;
  for (int z = 1; z < 7; z++) {
    j2.A[z] = nullptr; j2.BT[z] = nullptr; j2.bias[z] = nullptr; j2.C[z] = nullptr; j2.N[z] = 0;
  }
  hipLaunchKernelGGL(gemm_mf, dim3(8, 25, 1), dim3(256), 0, stream, j2);
}